// Round 1
// baseline (691.224 us; speedup 1.0000x reference)
//
#include <hip/hip_runtime.h>

#define N_NODES 50000
#define N_EDGES 800000
#define F_IN    128
#define R_REL   8
#define NR      (N_NODES * R_REL)        // 400000
#define SCAN_CHUNK 2048
#define SCAN_NBLK  ((NR + SCAN_CHUNK - 1) / SCAN_CHUNK)   // 196

// ---------------- CSR build ----------------

__global__ void k_hist(const int* __restrict__ dst, const int* __restrict__ et,
                       int* __restrict__ cnt) {
    int e = blockIdx.x * 256 + threadIdx.x;
    if (e < N_EDGES) atomicAdd(&cnt[dst[e] * R_REL + et[e]], 1);
}

__global__ void k_scan1(const int* __restrict__ cnt, int* __restrict__ offs,
                        int* __restrict__ bsum) {
    __shared__ int sd[256];
    int t = threadIdx.x;
    int base = blockIdx.x * SCAN_CHUNK + t * 8;
    int v[8];
    int tot = 0;
#pragma unroll
    for (int i = 0; i < 8; i++) {
        int idx = base + i;
        int xv = (idx < NR) ? cnt[idx] : 0;
        v[i] = tot;          // exclusive within thread
        tot += xv;
    }
    sd[t] = tot;
    __syncthreads();
    for (int off = 1; off < 256; off <<= 1) {
        int y = (t >= off) ? sd[t - off] : 0;
        __syncthreads();
        sd[t] += y;
        __syncthreads();
    }
    int excl = sd[t] - tot;  // exclusive prefix of thread totals
#pragma unroll
    for (int i = 0; i < 8; i++) {
        int idx = base + i;
        if (idx < NR) offs[idx] = v[i] + excl;
    }
    if (t == 255) bsum[blockIdx.x] = sd[255];
}

__global__ void k_scan2(const int* __restrict__ bsum, int* __restrict__ bsum2) {
    __shared__ int sd[256];
    int t = threadIdx.x;
    int v = (t < SCAN_NBLK) ? bsum[t] : 0;
    sd[t] = v;
    __syncthreads();
    for (int off = 1; off < 256; off <<= 1) {
        int y = (t >= off) ? sd[t - off] : 0;
        __syncthreads();
        sd[t] += y;
        __syncthreads();
    }
    bsum2[t] = sd[t] - v;    // exclusive
}

__global__ void k_scan3(int* __restrict__ offs, const int* __restrict__ bsum2,
                        int* __restrict__ cursor) {
    int t = threadIdx.x;
    int b = blockIdx.x;
    int add = bsum2[b];
    int base = b * SCAN_CHUNK + t * 8;
#pragma unroll
    for (int i = 0; i < 8; i++) {
        int idx = base + i;
        if (idx < NR) {
            int v = offs[idx] + add;
            offs[idx] = v;
            cursor[idx] = v;
        }
    }
    if (b == 0 && t == 0) offs[NR] = N_EDGES;
}

__global__ void k_scatter(const int* __restrict__ src, const int* __restrict__ dst,
                          const int* __restrict__ et, int* __restrict__ cursor,
                          int* __restrict__ srcS) {
    int e = blockIdx.x * 256 + threadIdx.x;
    if (e < N_EDGES) {
        int pos = atomicAdd(&cursor[dst[e] * R_REL + et[e]], 1);
        srcS[pos] = src[e];
    }
}

// ---------------- fused aggregate + GEMM layer ----------------
// Tile: 64 nodes x FOUT. Block 256 threads.
// A-tile stored K-major in LDS: As_t[k][row]  (conflict-free b128 reads in compute).
// seg 0 = root (identity "self edge"), segs 1..8 = relations (CSR gather + mean).

template <int FOUT, bool RELU>
__global__ __launch_bounds__(256) void k_layer(
    const float* __restrict__ xin,   // [N,128]
    const float* __restrict__ Wrel,  // [8,128,FOUT]
    const float* __restrict__ root,  // [128,FOUT]
    const float* __restrict__ bias,  // [FOUT]
    const int* __restrict__ offs,    // [NR+1]
    const int* __restrict__ srcS,    // [E]
    float* __restrict__ out)         // [N,FOUT]
{
    constexpr int CPT = FOUT / 16;   // cols per thread: 8 (L1) or 4 (L2)
    constexpr int NCG = CPT / 4;     // float4 col groups: 2 or 1
    __shared__ float As_t[128][68];  // [k][row], pad 68 (272B row, 16B aligned)
    __shared__ float Bs[32][FOUT];

    const int t = threadIdx.x;
    const int tc = t & 15;
    const int tr = t >> 4;
    const int node0 = blockIdx.x * 64;

    float acc[4][CPT];
#pragma unroll
    for (int i = 0; i < 4; i++)
#pragma unroll
        for (int g = 0; g < NCG; g++)
#pragma unroll
            for (int j = 0; j < 4; j++)
                acc[i][g * 4 + j] = bias[g * 64 + tc * 4 + j];

    // aggregation mapping: 4 lanes per node, 16 nodes per wave
    const int lane = t & 63;
    const int wave = t >> 6;
    const int nl = wave * 16 + (lane >> 2);  // 0..63 local node
    const int sub = lane & 3;                // feature quarter
    const int node = node0 + nl;

    for (int seg = 0; seg < 9; ++seg) {
        // ---- Phase A: build As_t (transposed A tile) ----
        {
            float a[8][4];
#pragma unroll
            for (int q = 0; q < 8; q++) {
                a[q][0] = 0.f; a[q][1] = 0.f; a[q][2] = 0.f; a[q][3] = 0.f;
            }
            int deg = 0;
            if (node < N_NODES) {
                int beg, end;
                if (seg == 0) { beg = 0; end = 1; }
                else {
                    int idx = node * R_REL + (seg - 1);
                    beg = offs[idx];
                    end = offs[idx + 1];
                }
                deg = end - beg;
                for (int j = beg; j < end; ++j) {
                    int s = (seg == 0) ? node : srcS[j];
                    const float* xr = xin + s * F_IN;
#pragma unroll
                    for (int q = 0; q < 8; q++) {
                        float4 v = *(const float4*)(xr + q * 16 + sub * 4);
                        a[q][0] += v.x; a[q][1] += v.y; a[q][2] += v.z; a[q][3] += v.w;
                    }
                }
            }
            float scl = 1.f / (float)(deg > 1 ? deg : 1);
#pragma unroll
            for (int q = 0; q < 8; q++)
#pragma unroll
                for (int i = 0; i < 4; i++)
                    As_t[q * 16 + sub * 4 + i][nl] = a[q][i] * scl;
        }

        const float* Bsrc = (seg == 0) ? root : (Wrel + (seg - 1) * (F_IN * FOUT));

        for (int kk = 0; kk < 4; ++kk) {
            // stage B chunk [32][FOUT]
            constexpr int LDV = (32 * FOUT) / 1024;  // float4 per thread: 4 or 2
#pragma unroll
            for (int i = 0; i < LDV; i++) {
                int f = i * 1024 + t * 4;
                int k = f / FOUT;
                int c = f % FOUT;
                *(float4*)&Bs[k][c] = *(const float4*)(Bsrc + (kk * 32 + k) * FOUT + c);
            }
            __syncthreads();  // As_t + Bs ready
#pragma unroll 8
            for (int k = 0; k < 32; k++) {
                float4 a4 = *(const float4*)&As_t[kk * 32 + k][tr * 4];
                float av[4] = {a4.x, a4.y, a4.z, a4.w};
                float bv[CPT];
#pragma unroll
                for (int g = 0; g < NCG; g++) {
                    float4 b4 = *(const float4*)&Bs[k][g * 64 + tc * 4];
                    bv[g * 4 + 0] = b4.x; bv[g * 4 + 1] = b4.y;
                    bv[g * 4 + 2] = b4.z; bv[g * 4 + 3] = b4.w;
                }
#pragma unroll
                for (int i = 0; i < 4; i++)
#pragma unroll
                    for (int j = 0; j < CPT; j++)
                        acc[i][j] += av[i] * bv[j];
            }
            __syncthreads();  // before Bs/As_t overwritten
        }
    }

    // ---- epilogue ----
#pragma unroll
    for (int i = 0; i < 4; i++) {
        int r = node0 + tr * 4 + i;
        if (r < N_NODES) {
#pragma unroll
            for (int g = 0; g < NCG; g++) {
                float4 v;
                v.x = acc[i][g * 4 + 0];
                v.y = acc[i][g * 4 + 1];
                v.z = acc[i][g * 4 + 2];
                v.w = acc[i][g * 4 + 3];
                if (RELU) {
                    v.x = fmaxf(v.x, 0.f); v.y = fmaxf(v.y, 0.f);
                    v.z = fmaxf(v.z, 0.f); v.w = fmaxf(v.w, 0.f);
                }
                *(float4*)(out + r * FOUT + g * 64 + tc * 4) = v;
            }
        }
    }
}

// ---------------- launch ----------------

extern "C" void kernel_launch(void* const* d_in, const int* in_sizes, int n_in,
                              void* d_out, int out_size, void* d_ws, size_t ws_size,
                              hipStream_t stream) {
    const float* x     = (const float*)d_in[0];
    const int*   ei    = (const int*)d_in[1];  // [2][E]: row0=src, row1=dst
    const int*   et    = (const int*)d_in[2];  // [E]
    const float* W1    = (const float*)d_in[3];
    const float* root1 = (const float*)d_in[4];
    const float* b1    = (const float*)d_in[5];
    const float* W2    = (const float*)d_in[6];
    const float* root2 = (const float*)d_in[7];
    const float* b2    = (const float*)d_in[8];
    float* out = (float*)d_out;

    int* ws     = (int*)d_ws;
    int* cnt    = ws;                  // NR
    int* offs   = cnt + NR;            // NR+1 (padded to NR+128)
    int* cursor = offs + NR + 128;     // NR
    int* bsum   = cursor + NR;         // 256
    int* bsum2  = bsum + 256;          // 256
    int* srcS   = bsum2 + 256;         // E
    float* h    = (float*)(srcS + N_EDGES);  // byte offset 8,002,560 (16B aligned)

    hipMemsetAsync(cnt, 0, NR * sizeof(int), stream);
    k_hist<<<(N_EDGES + 255) / 256, 256, 0, stream>>>(ei + N_EDGES, et, cnt);
    k_scan1<<<SCAN_NBLK, 256, 0, stream>>>(cnt, offs, bsum);
    k_scan2<<<1, 256, 0, stream>>>(bsum, bsum2);
    k_scan3<<<SCAN_NBLK, 256, 0, stream>>>(offs, bsum2, cursor);
    k_scatter<<<(N_EDGES + 255) / 256, 256, 0, stream>>>(ei, ei + N_EDGES, et, cursor, srcS);

    const int NTILES = (N_NODES + 63) / 64;  // 782
    k_layer<128, true ><<<NTILES, 256, 0, stream>>>(x, W1, root1, b1, offs, srcS, h);
    k_layer<64,  false><<<NTILES, 256, 0, stream>>>(h, W2, root2, b2, offs, srcS, out);
}

// Round 3
// 442.162 us; speedup vs baseline: 1.5633x; 1.5633x over previous
//
#include <hip/hip_runtime.h>

#define N_NODES 50000
#define N_EDGES 800000
#define R_REL   8
#define NR      (N_NODES * R_REL)        // 400000
#define SCAN_CHUNK 2048
#define SCAN_NBLK  ((NR + SCAN_CHUNK - 1) / SCAN_CHUNK)   // 196

typedef float  f32x4  __attribute__((ext_vector_type(4)));
typedef __bf16 bf16x8 __attribute__((ext_vector_type(8)));

__device__ __forceinline__ unsigned short f2bf(float f) {
    unsigned int u = __float_as_uint(f);
    u = (u + 0x7FFFu + ((u >> 16) & 1u)) >> 16;   // RNE
    return (unsigned short)u;
}
__device__ __forceinline__ float bflo(unsigned int u) { return __uint_as_float(u << 16); }
__device__ __forceinline__ float bfhi(unsigned int u) { return __uint_as_float(u & 0xFFFF0000u); }

// ---------------- CSR build ----------------

__global__ void k_hist(const int* __restrict__ dst, const int* __restrict__ et,
                       int* __restrict__ cnt) {
    int e = blockIdx.x * 256 + threadIdx.x;
    if (e < N_EDGES) atomicAdd(&cnt[dst[e] * R_REL + et[e]], 1);
}

__global__ void k_scan1(const int* __restrict__ cnt, int* __restrict__ offs,
                        int* __restrict__ bsum) {
    __shared__ int sd[256];
    int t = threadIdx.x;
    int base = blockIdx.x * SCAN_CHUNK + t * 8;
    int v[8];
    int tot = 0;
#pragma unroll
    for (int i = 0; i < 8; i++) {
        int idx = base + i;
        int xv = (idx < NR) ? cnt[idx] : 0;
        v[i] = tot;
        tot += xv;
    }
    sd[t] = tot;
    __syncthreads();
    for (int off = 1; off < 256; off <<= 1) {
        int y = (t >= off) ? sd[t - off] : 0;
        __syncthreads();
        sd[t] += y;
        __syncthreads();
    }
    int excl = sd[t] - tot;
#pragma unroll
    for (int i = 0; i < 8; i++) {
        int idx = base + i;
        if (idx < NR) offs[idx] = v[i] + excl;
    }
    if (t == 255) bsum[blockIdx.x] = sd[255];
}

__global__ void k_scan2(const int* __restrict__ bsum, int* __restrict__ bsum2) {
    __shared__ int sd[256];
    int t = threadIdx.x;
    int v = (t < SCAN_NBLK) ? bsum[t] : 0;
    sd[t] = v;
    __syncthreads();
    for (int off = 1; off < 256; off <<= 1) {
        int y = (t >= off) ? sd[t - off] : 0;
        __syncthreads();
        sd[t] += y;
        __syncthreads();
    }
    bsum2[t] = sd[t] - v;
}

__global__ void k_scan3(int* __restrict__ offs, const int* __restrict__ bsum2,
                        int* __restrict__ cursor) {
    int t = threadIdx.x;
    int b = blockIdx.x;
    int add = bsum2[b];
    int base = b * SCAN_CHUNK + t * 8;
#pragma unroll
    for (int i = 0; i < 8; i++) {
        int idx = base + i;
        if (idx < NR) {
            int v = offs[idx] + add;
            offs[idx] = v;
            cursor[idx] = v;
        }
    }
    if (b == 0 && t == 0) offs[NR] = N_EDGES;
}

__global__ void k_scatter(const int* __restrict__ src, const int* __restrict__ dst,
                          const int* __restrict__ et, int* __restrict__ cursor,
                          int* __restrict__ srcS) {
    int e = blockIdx.x * 256 + threadIdx.x;
    if (e < N_EDGES) {
        int pos = atomicAdd(&cursor[dst[e] * R_REL + et[e]], 1);
        srcS[pos] = src[e];
    }
}

// ---------------- converts ----------------

__global__ void k_cvt_x(const float* __restrict__ x, unsigned short* __restrict__ xb, int n4) {
    int i = blockIdx.x * 256 + threadIdx.x;
    if (i < n4) {
        float4 v = *(const float4*)(x + (size_t)i * 4);
        ushort4 o;
        o.x = f2bf(v.x); o.y = f2bf(v.y); o.z = f2bf(v.z); o.w = f2bf(v.w);
        *(ushort4*)(xb + (size_t)i * 4) = o;
    }
}

// Wt[seg][n][k] bf16, seg0 = root, segs 1..8 = W[r]. Input root[k][n], W[r][k][n].
template <int FOUT>
__global__ void k_wprep(const float* __restrict__ root, const float* __restrict__ W,
                        unsigned short* __restrict__ Wt) {
    int idx = blockIdx.x * 256 + threadIdx.x;
    if (idx >= 9 * FOUT * 128) return;
    int k = idx & 127;
    int rest = idx >> 7;       // seg*FOUT + n
    int n = rest % FOUT;
    int seg = rest / FOUT;
    float v = (seg == 0) ? root[k * FOUT + n] : W[((seg - 1) * 128 + k) * FOUT + n];
    Wt[idx] = f2bf(v);
}

// ---------------- fused aggregate + MFMA GEMM layer ----------------
// Tile: 32 nodes. Block = 128 threads = 2 waves; wave w owns rows w*16..w*16+15.
// Gather: 4 lanes per node (sub = t&3 owns k-range [sub*32, sub*32+32)).
// As[m][k] bf16, row stride 136 (272 B) -> A-frag b128 reads are 2-way (free).
// B frags read directly from global Wt (L1/L2-resident, 288/144 KB).

template <int FOUT, bool RELU, bool OUT_BF16>
__global__ __launch_bounds__(128, 4) void k_layer(
    const unsigned short* __restrict__ xb,   // [N,128] bf16
    const unsigned short* __restrict__ Wt,   // [9,FOUT,128] bf16
    const float* __restrict__ bias,          // [FOUT] fp32
    const int* __restrict__ offs,            // [NR+1]
    const int* __restrict__ srcS,            // [E]
    unsigned short* __restrict__ outb,       // [N,FOUT] bf16 (if OUT_BF16)
    float* __restrict__ outf)                // [N,FOUT] fp32 (else)
{
    constexpr int NB = FOUT / 16;
    __shared__ unsigned short As[32][136];

    const int t = threadIdx.x;
    const int node0 = blockIdx.x * 32;
    const int nl = t >> 2;        // local node 0..31
    const int sub = t & 3;        // k quarter: features [sub*32, sub*32+32)
    const int node = node0 + nl;
    const int lane = t & 63;
    const int w = t >> 6;         // wave 0..1
    const int quad = lane >> 4;
    const int tc = lane & 15;

    int ob[9];
    if (node < N_NODES) {
#pragma unroll
        for (int r = 0; r < 9; ++r) ob[r] = offs[node * 8 + r];
    } else {
#pragma unroll
        for (int r = 0; r < 9; ++r) ob[r] = 0;
    }

    f32x4 acc[NB];
#pragma unroll
    for (int nb = 0; nb < NB; ++nb) acc[nb] = (f32x4){0.f, 0.f, 0.f, 0.f};

    const unsigned short* Arow = &As[w * 16 + tc][0];

    for (int seg = 0; seg < 9; ++seg) {
        __syncthreads();   // previous MFMA reads of As done before overwrite

        float a[32];
#pragma unroll
        for (int i = 0; i < 32; ++i) a[i] = 0.f;
        int deg = 0;

        if (seg == 0) {
            if (node < N_NODES) {
                deg = 1;
                const uint4* xr = (const uint4*)(xb + (size_t)node * 128 + sub * 32);
#pragma unroll
                for (int q = 0; q < 4; ++q) {
                    uint4 v = xr[q];
                    a[q*8+0] += bflo(v.x); a[q*8+1] += bfhi(v.x);
                    a[q*8+2] += bflo(v.y); a[q*8+3] += bfhi(v.y);
                    a[q*8+4] += bflo(v.z); a[q*8+5] += bfhi(v.z);
                    a[q*8+6] += bflo(v.w); a[q*8+7] += bfhi(v.w);
                }
            }
        } else {
            int beg = ob[seg - 1], end = ob[seg];
            deg = end - beg;
            for (int j = beg; j < end; ++j) {
                int s = srcS[j];
                const uint4* xr = (const uint4*)(xb + (size_t)s * 128 + sub * 32);
#pragma unroll
                for (int q = 0; q < 4; ++q) {
                    uint4 v = xr[q];
                    a[q*8+0] += bflo(v.x); a[q*8+1] += bfhi(v.x);
                    a[q*8+2] += bflo(v.y); a[q*8+3] += bfhi(v.y);
                    a[q*8+4] += bflo(v.z); a[q*8+5] += bfhi(v.z);
                    a[q*8+6] += bflo(v.w); a[q*8+7] += bfhi(v.w);
                }
            }
        }

        // pack ALL 32 features (16 uints = 4 x uint4 = 64 bytes)
        float scl = 1.f / (float)(deg > 1 ? deg : 1);
        unsigned int pk[16];
#pragma unroll
        for (int i = 0; i < 16; ++i)
            pk[i] = (unsigned int)f2bf(a[i*2] * scl) |
                    ((unsigned int)f2bf(a[i*2+1] * scl) << 16);
        uint4* dstp = (uint4*)&As[nl][sub * 32];
        dstp[0] = make_uint4(pk[0],  pk[1],  pk[2],  pk[3]);
        dstp[1] = make_uint4(pk[4],  pk[5],  pk[6],  pk[7]);
        dstp[2] = make_uint4(pk[8],  pk[9],  pk[10], pk[11]);
        dstp[3] = make_uint4(pk[12], pk[13], pk[14], pk[15]);

        __syncthreads();   // As ready

        const unsigned short* Bbase = Wt + (size_t)seg * FOUT * 128 + quad * 8;
#pragma unroll
        for (int kk = 0; kk < 4; ++kk) {
            bf16x8 af = *(const bf16x8*)(Arow + kk * 32 + quad * 8);
#pragma unroll
            for (int nb = 0; nb < NB; ++nb) {
                bf16x8 bf = *(const bf16x8*)(Bbase + (nb * 16 + tc) * 128 + kk * 32);
                acc[nb] = __builtin_amdgcn_mfma_f32_16x16x32_bf16(af, bf, acc[nb], 0, 0, 0);
            }
        }
    }

    // epilogue: D layout col = lane&15, row = quad*4 + reg
#pragma unroll
    for (int nb = 0; nb < NB; ++nb) {
        int col = nb * 16 + tc;
        float bs = bias[col];
#pragma unroll
        for (int i = 0; i < 4; ++i) {
            int r = node0 + w * 16 + quad * 4 + i;
            if (r < N_NODES) {
                float v = acc[nb][i] + bs;
                if (RELU) v = fmaxf(v, 0.f);
                if (OUT_BF16) outb[(size_t)r * FOUT + col] = f2bf(v);
                else          outf[(size_t)r * FOUT + col] = v;
            }
        }
    }
}

// ---------------- launch ----------------

extern "C" void kernel_launch(void* const* d_in, const int* in_sizes, int n_in,
                              void* d_out, int out_size, void* d_ws, size_t ws_size,
                              hipStream_t stream) {
    const float* x     = (const float*)d_in[0];
    const int*   ei    = (const int*)d_in[1];  // [2][E]: row0=src, row1=dst
    const int*   et    = (const int*)d_in[2];  // [E]
    const float* W1    = (const float*)d_in[3];
    const float* root1 = (const float*)d_in[4];
    const float* b1    = (const float*)d_in[5];
    const float* W2    = (const float*)d_in[6];
    const float* root2 = (const float*)d_in[7];
    const float* b2    = (const float*)d_in[8];
    float* out = (float*)d_out;

    int* ws     = (int*)d_ws;
    int* cnt    = ws;                  // NR  (reused for Wt1 after scans)
    int* offs   = cnt + NR;            // NR+1 (padded to NR+128)
    int* cursor = offs + NR + 128;     // NR  (reused for Wt2 after scatter)
    int* bsum   = cursor + NR;         // 256
    int* bsum2  = bsum + 256;          // 256
    int* srcS   = bsum2 + 256;         // E
    unsigned short* xb = (unsigned short*)(srcS + N_EDGES);  // [N,128] bf16
    unsigned short* hb = xb + (size_t)N_NODES * 128;         // [N,128] bf16
    unsigned short* Wt1 = (unsigned short*)cnt;              // 288 KB < 1.6 MB
    unsigned short* Wt2 = (unsigned short*)cursor;           // 144 KB < 1.6 MB

    hipMemsetAsync(cnt, 0, NR * sizeof(int), stream);
    k_hist<<<(N_EDGES + 255) / 256, 256, 0, stream>>>(ei + N_EDGES, et, cnt);
    k_scan1<<<SCAN_NBLK, 256, 0, stream>>>(cnt, offs, bsum);
    k_scan2<<<1, 256, 0, stream>>>(bsum, bsum2);
    k_scan3<<<SCAN_NBLK, 256, 0, stream>>>(offs, bsum2, cursor);
    k_scatter<<<(N_EDGES + 255) / 256, 256, 0, stream>>>(ei, ei + N_EDGES, et, cursor, srcS);

    // cnt dead after k_scan1, cursor dead after k_scatter -> safe to overwrite now
    k_wprep<128><<<(9 * 128 * 128 + 255) / 256, 256, 0, stream>>>(root1, W1, Wt1);
    k_wprep<64><<<(9 * 64 * 128 + 255) / 256, 256, 0, stream>>>(root2, W2, Wt2);
    k_cvt_x<<<(N_NODES * 32 + 255) / 256, 256, 0, stream>>>(x, xb, N_NODES * 32);

    const int NT = (N_NODES + 31) / 32;  // 1563
    k_layer<128, true,  true ><<<NT, 128, 0, stream>>>(xb, Wt1, b1, offs, srcS, hb, nullptr);
    k_layer<64,  false, false><<<NT, 128, 0, stream>>>(hb, Wt2, b2, offs, srcS, nullptr, out);
}

// Round 4
// 427.568 us; speedup vs baseline: 1.6166x; 1.0341x over previous
//
#include <hip/hip_runtime.h>

#define N_NODES 50000
#define N_EDGES 800000
#define R_REL   8
#define NR      (N_NODES * R_REL)        // 400000
#define SCAN_CHUNK 2048
#define SCAN_NBLK  ((NR + SCAN_CHUNK - 1) / SCAN_CHUNK)   // 196

typedef float  f32x4  __attribute__((ext_vector_type(4)));
typedef __bf16 bf16x8 __attribute__((ext_vector_type(8)));

__device__ __forceinline__ unsigned short f2bf(float f) {
    unsigned int u = __float_as_uint(f);
    u = (u + 0x7FFFu + ((u >> 16) & 1u)) >> 16;   // RNE
    return (unsigned short)u;
}
__device__ __forceinline__ float bflo(unsigned int u) { return __uint_as_float(u << 16); }
__device__ __forceinline__ float bfhi(unsigned int u) { return __uint_as_float(u & 0xFFFF0000u); }

__device__ __forceinline__ void acc16(float* a, uint4 u0, uint4 u1, float m) {
    a[0]  = fmaf(bflo(u0.x), m, a[0]);   a[1]  = fmaf(bfhi(u0.x), m, a[1]);
    a[2]  = fmaf(bflo(u0.y), m, a[2]);   a[3]  = fmaf(bfhi(u0.y), m, a[3]);
    a[4]  = fmaf(bflo(u0.z), m, a[4]);   a[5]  = fmaf(bfhi(u0.z), m, a[5]);
    a[6]  = fmaf(bflo(u0.w), m, a[6]);   a[7]  = fmaf(bfhi(u0.w), m, a[7]);
    a[8]  = fmaf(bflo(u1.x), m, a[8]);   a[9]  = fmaf(bfhi(u1.x), m, a[9]);
    a[10] = fmaf(bflo(u1.y), m, a[10]);  a[11] = fmaf(bfhi(u1.y), m, a[11]);
    a[12] = fmaf(bflo(u1.z), m, a[12]);  a[13] = fmaf(bfhi(u1.z), m, a[13]);
    a[14] = fmaf(bflo(u1.w), m, a[14]);  a[15] = fmaf(bfhi(u1.w), m, a[15]);
}

// ---------------- CSR build ----------------

__global__ void k_hist(const int* __restrict__ dst, const int* __restrict__ et,
                       int* __restrict__ cnt) {
    int e = blockIdx.x * 256 + threadIdx.x;
    if (e < N_EDGES) atomicAdd(&cnt[dst[e] * R_REL + et[e]], 1);
}

__global__ void k_scan1(const int* __restrict__ cnt, int* __restrict__ offs,
                        int* __restrict__ bsum) {
    __shared__ int sd[256];
    int t = threadIdx.x;
    int base = blockIdx.x * SCAN_CHUNK + t * 8;
    int v[8];
    int tot = 0;
#pragma unroll
    for (int i = 0; i < 8; i++) {
        int idx = base + i;
        int xv = (idx < NR) ? cnt[idx] : 0;
        v[i] = tot;
        tot += xv;
    }
    sd[t] = tot;
    __syncthreads();
    for (int off = 1; off < 256; off <<= 1) {
        int y = (t >= off) ? sd[t - off] : 0;
        __syncthreads();
        sd[t] += y;
        __syncthreads();
    }
    int excl = sd[t] - tot;
#pragma unroll
    for (int i = 0; i < 8; i++) {
        int idx = base + i;
        if (idx < NR) offs[idx] = v[i] + excl;
    }
    if (t == 255) bsum[blockIdx.x] = sd[255];
}

__global__ void k_scan2(const int* __restrict__ bsum, int* __restrict__ bsum2) {
    __shared__ int sd[256];
    int t = threadIdx.x;
    int v = (t < SCAN_NBLK) ? bsum[t] : 0;
    sd[t] = v;
    __syncthreads();
    for (int off = 1; off < 256; off <<= 1) {
        int y = (t >= off) ? sd[t - off] : 0;
        __syncthreads();
        sd[t] += y;
        __syncthreads();
    }
    bsum2[t] = sd[t] - v;
}

__global__ void k_scan3(int* __restrict__ offs, const int* __restrict__ bsum2,
                        int* __restrict__ cursor) {
    int t = threadIdx.x;
    int b = blockIdx.x;
    int add = bsum2[b];
    int base = b * SCAN_CHUNK + t * 8;
#pragma unroll
    for (int i = 0; i < 8; i++) {
        int idx = base + i;
        if (idx < NR) {
            int v = offs[idx] + add;
            offs[idx] = v;
            cursor[idx] = v;
        }
    }
    if (b == 0 && t == 0) offs[NR] = N_EDGES;
}

__global__ void k_scatter(const int* __restrict__ src, const int* __restrict__ dst,
                          const int* __restrict__ et, int* __restrict__ cursor,
                          int* __restrict__ srcS) {
    int e = blockIdx.x * 256 + threadIdx.x;
    if (e < N_EDGES) {
        int pos = atomicAdd(&cursor[dst[e] * R_REL + et[e]], 1);
        srcS[pos] = src[e];
    }
}

// ---------------- converts ----------------

__global__ void k_cvt_x(const float* __restrict__ x, unsigned short* __restrict__ xb, int n4) {
    int i = blockIdx.x * 256 + threadIdx.x;
    if (i < n4) {
        float4 v = *(const float4*)(x + (size_t)i * 4);
        ushort4 o;
        o.x = f2bf(v.x); o.y = f2bf(v.y); o.z = f2bf(v.z); o.w = f2bf(v.w);
        *(ushort4*)(xb + (size_t)i * 4) = o;
    }
}

// Wt[seg][n][k] bf16, seg0 = root, segs 1..8 = W[r]. Input root[k][n], W[r][k][n].
template <int FOUT>
__global__ void k_wprep(const float* __restrict__ root, const float* __restrict__ W,
                        unsigned short* __restrict__ Wt) {
    int idx = blockIdx.x * 256 + threadIdx.x;
    if (idx >= 9 * FOUT * 128) return;
    int k = idx & 127;
    int rest = idx >> 7;       // seg*FOUT + n
    int n = rest % FOUT;
    int seg = rest / FOUT;
    float v = (seg == 0) ? root[k * FOUT + n] : W[((seg - 1) * 128 + k) * FOUT + n];
    Wt[idx] = f2bf(v);
}

// ---------------- fused aggregate + MFMA GEMM layer ----------------
// Tile: 32 nodes, 256 threads (4 waves).
// Gather: 8 threads/node (sub = t&7, 16 feats each), 4-wide edge batching
//   (chain depth ceil(deg/4); clamped dup loads are L1 hits).
// As double-buffered -> 1 barrier/seg; gather of seg s+1 overlaps MFMA of s.
// MFMA split: wave w -> rows (w&1)*16.., nb half (w>>1).
// B frags read directly from global Wt (L2-resident, 288/144 KB).

template <int FOUT, bool RELU, bool OUT_BF16>
__global__ __launch_bounds__(256, 4) void k_layer(
    const unsigned short* __restrict__ xb,   // [N,128] bf16
    const unsigned short* __restrict__ Wt,   // [9,FOUT,128] bf16
    const float* __restrict__ bias,          // [FOUT] fp32
    const int* __restrict__ offs,            // [NR+1]
    const int* __restrict__ srcS,            // [E]
    unsigned short* __restrict__ outb,       // [N,FOUT] bf16 (if OUT_BF16)
    float* __restrict__ outf)                // [N,FOUT] fp32 (else)
{
    constexpr int NBW = FOUT / 32;           // nb tiles per wave (4 or 2)
    __shared__ unsigned short As[2][32][136];

    const int t = threadIdx.x;
    const int node0 = blockIdx.x * 32;
    const int nl  = t >> 3;       // local node 0..31
    const int sub = t & 7;        // 16-feature slice [sub*16, sub*16+16)
    const int node = node0 + nl;
    const int lane = t & 63;
    const int w = t >> 6;         // wave 0..3
    const int quad = lane >> 4;
    const int tc = lane & 15;
    const int rbase = (w & 1) * 16;
    const int nb0 = (w >> 1) * NBW;

    int ob[9];
    if (node < N_NODES) {
#pragma unroll
        for (int r = 0; r < 9; ++r) ob[r] = offs[node * 8 + r];
    } else {
#pragma unroll
        for (int r = 0; r < 9; ++r) ob[r] = 0;
    }

    f32x4 acc[NBW];
#pragma unroll
    for (int nb = 0; nb < NBW; ++nb) acc[nb] = (f32x4){0.f, 0.f, 0.f, 0.f};

    for (int seg = 0; seg < 9; ++seg) {
        float a[16];
#pragma unroll
        for (int i = 0; i < 16; ++i) a[i] = 0.f;
        int deg = 0;

        if (seg == 0) {
            if (node < N_NODES) {
                deg = 1;
                const uint4* xr = (const uint4*)(xb + (size_t)node * 128 + sub * 16);
                acc16(a, xr[0], xr[1], 1.f);
            }
        } else {
            int beg = ob[seg - 1], end = ob[seg];
            deg = end - beg;
            if (deg > 0) {
                int last = end - 1;
                for (int j = beg; j < end; j += 4) {
                    int j1 = (j + 1 < end) ? j + 1 : last;
                    int j2 = (j + 2 < end) ? j + 2 : last;
                    int j3 = (j + 3 < end) ? j + 3 : last;
                    int s0 = srcS[j];
                    int s1 = srcS[j1];
                    int s2 = srcS[j2];
                    int s3 = srcS[j3];
                    const uint4* p0 = (const uint4*)(xb + (size_t)s0 * 128 + sub * 16);
                    const uint4* p1 = (const uint4*)(xb + (size_t)s1 * 128 + sub * 16);
                    const uint4* p2 = (const uint4*)(xb + (size_t)s2 * 128 + sub * 16);
                    const uint4* p3 = (const uint4*)(xb + (size_t)s3 * 128 + sub * 16);
                    uint4 v0a = p0[0], v0b = p0[1];
                    uint4 v1a = p1[0], v1b = p1[1];
                    uint4 v2a = p2[0], v2b = p2[1];
                    uint4 v3a = p3[0], v3b = p3[1];
                    float m1 = (j + 1 < end) ? 1.f : 0.f;
                    float m2 = (j + 2 < end) ? 1.f : 0.f;
                    float m3 = (j + 3 < end) ? 1.f : 0.f;
                    acc16(a, v0a, v0b, 1.f);
                    acc16(a, v1a, v1b, m1);
                    acc16(a, v2a, v2b, m2);
                    acc16(a, v3a, v3b, m3);
                }
            }
        }

        // pack 16 feats -> 8 uints -> 2 uint4 stores
        float scl = 1.f / (float)(deg > 1 ? deg : 1);
        unsigned int pk[8];
#pragma unroll
        for (int i = 0; i < 8; ++i)
            pk[i] = (unsigned int)f2bf(a[i * 2] * scl) |
                    ((unsigned int)f2bf(a[i * 2 + 1] * scl) << 16);
        uint4* dstp = (uint4*)&As[seg & 1][nl][sub * 16];
        dstp[0] = make_uint4(pk[0], pk[1], pk[2], pk[3]);
        dstp[1] = make_uint4(pk[4], pk[5], pk[6], pk[7]);

        __syncthreads();   // As[seg&1] ready (prev buffer's MFMA reads already done)

        const unsigned short* Arow = &As[seg & 1][rbase + tc][0];
        const unsigned short* Bbase = Wt + (size_t)seg * FOUT * 128 + quad * 8;
#pragma unroll
        for (int kk = 0; kk < 4; ++kk) {
            bf16x8 af = *(const bf16x8*)(Arow + kk * 32 + quad * 8);
#pragma unroll
            for (int nb = 0; nb < NBW; ++nb) {
                bf16x8 bf = *(const bf16x8*)(Bbase + ((nb0 + nb) * 16 + tc) * 128 + kk * 32);
                acc[nb] = __builtin_amdgcn_mfma_f32_16x16x32_bf16(af, bf, acc[nb], 0, 0, 0);
            }
        }
    }

    // epilogue: D layout col = lane&15, row = quad*4 + reg
#pragma unroll
    for (int nb = 0; nb < NBW; ++nb) {
        int col = (nb0 + nb) * 16 + tc;
        float bs = bias[col];
#pragma unroll
        for (int i = 0; i < 4; ++i) {
            int r = node0 + rbase + quad * 4 + i;
            if (r < N_NODES) {
                float v = acc[nb][i] + bs;
                if (RELU) v = fmaxf(v, 0.f);
                if (OUT_BF16) outb[(size_t)r * FOUT + col] = f2bf(v);
                else          outf[(size_t)r * FOUT + col] = v;
            }
        }
    }
}

// ---------------- launch ----------------

extern "C" void kernel_launch(void* const* d_in, const int* in_sizes, int n_in,
                              void* d_out, int out_size, void* d_ws, size_t ws_size,
                              hipStream_t stream) {
    const float* x     = (const float*)d_in[0];
    const int*   ei    = (const int*)d_in[1];  // [2][E]: row0=src, row1=dst
    const int*   et    = (const int*)d_in[2];  // [E]
    const float* W1    = (const float*)d_in[3];
    const float* root1 = (const float*)d_in[4];
    const float* b1    = (const float*)d_in[5];
    const float* W2    = (const float*)d_in[6];
    const float* root2 = (const float*)d_in[7];
    const float* b2    = (const float*)d_in[8];
    float* out = (float*)d_out;

    int* ws     = (int*)d_ws;
    int* cnt    = ws;                  // NR  (reused for Wt1 after scans)
    int* offs   = cnt + NR;            // NR+1 (padded to NR+128)
    int* cursor = offs + NR + 128;     // NR  (reused for Wt2 after scatter)
    int* bsum   = cursor + NR;         // 256
    int* bsum2  = bsum + 256;          // 256
    int* srcS   = bsum2 + 256;         // E
    unsigned short* xb = (unsigned short*)(srcS + N_EDGES);  // [N,128] bf16
    unsigned short* hb = xb + (size_t)N_NODES * 128;         // [N,128] bf16
    unsigned short* Wt1 = (unsigned short*)cnt;              // 288 KB < 1.6 MB
    unsigned short* Wt2 = (unsigned short*)cursor;           // 144 KB < 1.6 MB

    hipMemsetAsync(cnt, 0, NR * sizeof(int), stream);
    k_hist<<<(N_EDGES + 255) / 256, 256, 0, stream>>>(ei + N_EDGES, et, cnt);
    k_scan1<<<SCAN_NBLK, 256, 0, stream>>>(cnt, offs, bsum);
    k_scan2<<<1, 256, 0, stream>>>(bsum, bsum2);
    k_scan3<<<SCAN_NBLK, 256, 0, stream>>>(offs, bsum2, cursor);
    k_scatter<<<(N_EDGES + 255) / 256, 256, 0, stream>>>(ei, ei + N_EDGES, et, cursor, srcS);

    // cnt dead after k_scan1, cursor dead after k_scatter -> safe to overwrite now
    k_wprep<128><<<(9 * 128 * 128 + 255) / 256, 256, 0, stream>>>(root1, W1, Wt1);
    k_wprep<64><<<(9 * 64 * 128 + 255) / 256, 256, 0, stream>>>(root2, W2, Wt2);
    k_cvt_x<<<(N_NODES * 32 + 255) / 256, 256, 0, stream>>>(x, xb, N_NODES * 32);

    const int NT = (N_NODES + 31) / 32;  // 1563
    k_layer<128, true,  true ><<<NT, 256, 0, stream>>>(xb, Wt1, b1, offs, srcS, hb, nullptr);
    k_layer<64,  false, false><<<NT, 256, 0, stream>>>(hb, Wt2, b2, offs, srcS, nullptr, out);
}